// Round 15
// baseline (87.283 us; speedup 1.0000x reference)
//
#include <hip/hip_runtime.h>
#include <hip/hip_bf16.h>

#define BATCH 4096
#define FIELDS_ 39
#define NUMF 13
#define CATF 26
#define DD 16
#define MM 16
#define VV 100000
#define DEEP_ 400
#define QQ 741
#define QPAD 768
#define KE 624      // FIELDS*D
#define KEP 640     // padded K for emb branch
#define NEP 512     // padded N for emb branch
#define N1 6400     // DEEP*M (n = kcol*16 + m)
#define EPS_ 1e-5f

// workspace layout (float offsets)
#define OFF_ABF 0                            // ushort A[b][768] row-major
#define OFF_T   (BATCH*QPAD/2)               // f32 softmax[b][m] (t2s folded into W2)
#define OFF_W2  (OFF_T + BATCH*MM)           // ushort W2[n][768] row-major, pre-scaled by t2s[m]
#define OFF_WE  (OFF_W2 + N1*QPAD/2)         // ushort WE[n][640] row-major (n pad 512)
#define OFF_FMB (OFF_WE + NEP*KEP/2)         // ushort fm2[b][k] stride KEP
#define OFF_TH  (OFF_FMB + BATCH*KEP/2)      // f32 th_pre[b][400]
#define OFF_EMB (OFF_TH + BATCH*DEEP_)       // f32 emb_pre[b][400]
#define OFF_ACC (OFF_EMB + BATCH*DEEP_)      // [0:800] sums, [800:1600] sumsq

typedef __attribute__((ext_vector_type(8))) short bf16x8;
typedef __attribute__((ext_vector_type(16))) float f32x16;

__device__ __forceinline__ ushort f2bf(float v) {
    union { float f; unsigned u; } x; x.f = v;
    unsigned r = x.u + 0x7fff + ((x.u >> 16) & 1);
    return (ushort)(r >> 16);
}
__device__ __forceinline__ unsigned pack2(float a, float b) {
    return (unsigned)f2bf(a) | ((unsigned)f2bf(b) << 16);
}
__device__ __forceinline__ void async16(void* lds, const void* g) {
    __builtin_amdgcn_global_load_lds(
        (const __attribute__((address_space(1))) unsigned int*)g,
        (__attribute__((address_space(3))) unsigned int*)lds,
        16, 0, 0);
}

// ---------------- merged: feat | W2 transpose+scale | WE transpose (R11) -------
__global__ __launch_bounds__(256) void kbig(const int* __restrict__ xi,
                                            const float* __restrict__ xv,
                                            const float* __restrict__ emb,
                                            const float* __restrict__ gc,
                                            const float* __restrict__ fi_w,
                                            const float* __restrict__ emb_w,
                                            const float* __restrict__ T3,
                                            const float* __restrict__ T2,
                                            float* __restrict__ ws,
                                            ushort* __restrict__ Abf,
                                            ushort* __restrict__ FMB,
                                            ushort* __restrict__ W2,
                                            ushort* __restrict__ WE) {
    __shared__ float smem[4200];
    int bid = blockIdx.x, tid = threadIdx.x;

    if (bid < BATCH) {
        float* row = smem;
        float* hsh = smem + 624;
        float* gash = smem + 640;
        ushort* stA = (ushort*)(smem + 656);
        ushort* stF = stA + QPAD;
        int b = bid;
        for (int e = tid; e < KE; e += 256) {
            int f = e >> 4, d = e & 15;
            float v;
            if (f < NUMF) {
                v = xv[b * NUMF + f] * emb[(long)f * VV * DD + d];
            } else {
                int c = f - NUMF;
                int idxv = xi[b * CATF + c];
                v = emb[((long)(NUMF + c) * VV + idxv) * DD + d];
            }
            row[e] = v;
        }
        __syncthreads();
        for (int e = tid; e < KEP; e += 256)
            stF[e] = (e < KE) ? f2bf(row[e]) : (ushort)0;
        if (tid < DD) {
            float s = 0.f, s2 = 0.f;
            for (int f = 0; f < FIELDS_; ++f) { float v = row[f * DD + tid]; s += v; s2 += v * v; }
            hsh[tid] = 0.5f * (s * s - s2);
        }
        __syncthreads();
        if (tid < MM) {
            float g = 0.f;
            for (int d = 0; d < DD; ++d) g += hsh[d] * T3[(d * MM + tid) * DD + d];
            gash[tid] = g;
        }
        __syncthreads();
        if (tid < MM) {
            float mx = -1e30f;
            for (int m = 0; m < MM; ++m) mx = fmaxf(mx, gash[m]);
            float se = 0.f;
            for (int m = 0; m < MM; ++m) se += expf(gash[m] - mx);
            ws[OFF_T + b * MM + tid] = expf(gash[tid] - mx) / se;
        }
        for (int q = tid; q < QPAD; q += 256) {
            float av = 0.f;
            if (q < QQ) {
                int i = 0, qq = q, cnt = FIELDS_ - 1;
                while (qq >= cnt) { qq -= cnt; ++i; cnt = FIELDS_ - 1 - i; }
                int j = i + 1 + qq;
                const float4* ri = (const float4*)&row[i * DD];
                const float4* rj = (const float4*)&row[j * DD];
                float4 a0 = ri[0], a1 = ri[1], a2 = ri[2], a3 = ri[3];
                float4 b0 = rj[0], b1 = rj[1], b2 = rj[2], b3 = rj[3];
                float dot = a0.x * b0.x + a0.y * b0.y + a0.z * b0.z + a0.w * b0.w
                          + a1.x * b1.x + a1.y * b1.y + a1.z * b1.z + a1.w * b1.w
                          + a2.x * b2.x + a2.y * b2.y + a2.z * b2.z + a2.w * b2.w
                          + a3.x * b3.x + a3.y * b3.y + a3.z * b3.z + a3.w * b3.w;
                av = dot * gc[q];
            }
            stA[q] = f2bf(av);
        }
        __syncthreads();
        if (tid < 96)
            *(uint4*)&Abf[(long)b * QPAD + tid * 8] = *(uint4*)&stA[tid * 8];
        else if (tid < 176)
            *(uint4*)&FMB[(long)b * KEP + (tid - 96) * 8] = *(uint4*)&stF[(tid - 96) * 8];
    } else if (bid < BATCH + 1536) {
        int bt = bid - BATCH;
        int kt = bt >> 6, m = (bt >> 2) & 15, ch = bt & 3;
        float* tile = smem;
        {
            float p = T2[m * DD * DD + tid];
#pragma unroll
            for (int off = 32; off > 0; off >>= 1) p += __shfl_down(p, off, 64);
            if ((tid & 63) == 0) smem[4100 + (tid >> 6)] = p;
        }
        for (int i = tid; i < 32 * 25; i += 256) {
            int ql = i / 25, c4 = i - ql * 25;
            int q = kt * 32 + ql;
            float4 v = make_float4(0.f, 0.f, 0.f, 0.f);
            if (q < QQ) v = *(const float4*)&fi_w[(q * MM + m) * DEEP_ + ch * 100 + c4 * 4];
            tile[ql * 101 + c4 * 4 + 0] = v.x; tile[ql * 101 + c4 * 4 + 1] = v.y;
            tile[ql * 101 + c4 * 4 + 2] = v.z; tile[ql * 101 + c4 * 4 + 3] = v.w;
        }
        __syncthreads();
        float t2s = smem[4100] + smem[4101] + smem[4102] + smem[4103];
        for (int i = tid; i < 100 * 4; i += 256) {
            int lc = i >> 2, cq = i & 3;
            int kcol = ch * 100 + lc;
            unsigned r[4];
#pragma unroll
            for (int j = 0; j < 4; ++j)
                r[j] = pack2(tile[(cq * 8 + 2 * j) * 101 + lc] * t2s,
                             tile[(cq * 8 + 2 * j + 1) * 101 + lc] * t2s);
            *(uint4*)&W2[(long)(kcol * 16 + m) * QPAD + kt * 32 + cq * 8] =
                make_uint4(r[0], r[1], r[2], r[3]);
        }
    } else {
        int bt = bid - BATCH - 1536;
        if (bt == 0) {
            for (int i = tid; i < 1600; i += 256) ws[OFF_ACC + i] = 0.f;
        }
        int kt = bt >> 2, ch = bt & 3;
        float* tile = smem;
        for (int i = tid; i < 32 * 32; i += 256) {
            int kl = i >> 5, c4 = i & 31;
            int k = kt * 32 + kl;
            int n = ch * 128 + c4 * 4;
            float4 v = make_float4(0.f, 0.f, 0.f, 0.f);
            if (k < KE && n < DEEP_) v = *(const float4*)&emb_w[k * DEEP_ + n];
            tile[kl * 129 + c4 * 4 + 0] = v.x; tile[kl * 129 + c4 * 4 + 1] = v.y;
            tile[kl * 129 + c4 * 4 + 2] = v.z; tile[kl * 129 + c4 * 4 + 3] = v.w;
        }
        __syncthreads();
        for (int i = tid; i < 128 * 4; i += 256) {
            int nl = i >> 2, cq = i & 3;
            int n = ch * 128 + nl;
            uint4 o = make_uint4(0, 0, 0, 0);
            if (n < DEEP_) {
                unsigned r[4];
#pragma unroll
                for (int j = 0; j < 4; ++j)
                    r[j] = pack2(tile[(cq * 8 + 2 * j) * 129 + nl], tile[(cq * 8 + 2 * j + 1) * 129 + nl]);
                o = make_uint4(r[0], r[1], r[2], r[3]);
            }
            if (n < NEP)
                *(uint4*)&WE[(long)n * KEP + kt * 32 + cq * 8] = o;
        }
    }
}

// ---------------- unified GEMM: 8-phase, 32x32x16 MFMA -------------------------
// Same staging/phase skeleton as R14; MFMA shape switched to 32x32x16 (2495 vs
// 2075 TF ubench -> ~17% less matrix-pipe time, identical ds_read bytes).
// Per wave 128(f1)x64(f2) = 4x2 sub-tiles of 32x32; per K-tile 4 K-steps of 16.
// f1 lane layout: row = base + (lane&31), k = (lane>>5)*8 + j (chunk 2*ks+h).
// C/D: col = lane&31, row = (reg&3) + 8*(reg>>2) + 4*(lane>>5)  [m74/m101].
__global__ __launch_bounds__(512, 1) void kgemms(const ushort* __restrict__ Abf,
                                                 const ushort* __restrict__ W2,
                                                 const ushort* __restrict__ FMB,
                                                 const ushort* __restrict__ WE,
                                                 const float* __restrict__ Tmat,
                                                 float* __restrict__ TH,
                                                 float* __restrict__ EMB,
                                                 float* __restrict__ ACC) {
    __shared__ ushort ldsbuf[65536];   // 128 KB: two 32768-ushort K-tile buffers
    int tid = threadIdx.x;
    int lane = tid & 63, wid = tid >> 6;
    int wB = wid >> 2;        // 0..1: 128-row side (f1 / mat1)
    int wS = wid & 3;         // 0..3: 64-row side (f2 / mat0)
    int l31 = lane & 31, h = lane >> 5, l7 = lane & 7;
    f32x16 acc[4][2] = {};
    int wg = blockIdx.x;

    long stride; const ushort *m0, *m1; int ntiles;
    int b0, n0;
    bool main_ = (wg < 400);
    if (main_) {
        int L = (wg & 7) * 50 + (wg >> 3);     // XCD-chunked, bijective (400 = 8*50)
        n0 = (L >> 4) * 256;
        b0 = (L & 15) * 256;
        m0 = Abf + (long)b0 * QPAD;   // f2-side (A rows)
        m1 = W2 + (long)n0 * QPAD;    // f1-side (W rows)
        stride = QPAD; ntiles = 12;
    } else {
        int e = wg - 400;
        int se = (e & 7) * 4 + (e >> 3);
        b0 = (se >> 1) * 256;
        n0 = (se & 1) * 256;
        m0 = WE + (long)n0 * KEP;     // f2-side (WE rows)
        m1 = FMB + (long)b0 * KEP;    // f1-side (FMB rows)
        stride = KEP; ntiles = 10;
    }

    // staging: lane-linear LDS dest, pre-swizzled global src (pos p holds chunk p^(row&7))
    int cst = tid & 7, rl = tid >> 3;
    int rowB_off = rl + ((rl & 32) ? 96 : 0);

#define STAGE1(TILE, SEG) { \
    int row_, mat_; \
    if ((SEG) < 4) { mat_ = 0; row_ = (SEG) * 64 + rl; } \
    else { mat_ = 1; row_ = ((SEG) - 4) * 32 + rowB_off; } \
    int co_ = cst ^ (row_ & 7); \
    const ushort* src_ = (mat_ ? m1 : m0) + (long)row_ * stride + (TILE) * 64 + co_ * 8; \
    async16(&ldsbuf[((TILE) & 1) * 32768 + mat_ * 16384 + row_ * 64 + cst * 8], src_); }

    // fragment read offsets (ushort units); chunk for kstep ks = 2*ks + h
    int pos0 = ((0 + h) ^ l7) * 8;
    int pos1 = ((2 + h) ^ l7) * 8;
    int pos2 = ((4 + h) ^ l7) * 8;
    int pos3 = ((6 + h) ^ l7) * 8;
    int a_off = (wS * 64 + l31) * 64;            // mat0 region (f2 rows)
    int b_off = 16384 + (wB * 128 + l31) * 64;   // mat1 region (f1 rows)

    bf16x8 f2r[2][4];   // [t][ks]

#define PHASE(BUFI, S, DOF2, STG, VMC) { \
    const ushort* bp_ = &ldsbuf[(BUFI) * 32768]; \
    if (DOF2) { \
        _Pragma("unroll") for (int t_ = 0; t_ < 2; ++t_) { \
            f2r[t_][0] = *(const bf16x8*)&bp_[a_off + t_ * 2048 + pos0]; \
            f2r[t_][1] = *(const bf16x8*)&bp_[a_off + t_ * 2048 + pos1]; \
            f2r[t_][2] = *(const bf16x8*)&bp_[a_off + t_ * 2048 + pos2]; \
            f2r[t_][3] = *(const bf16x8*)&bp_[a_off + t_ * 2048 + pos3]; } } \
    bf16x8 f1_[4]; \
    f1_[0] = *(const bf16x8*)&bp_[b_off + (S) * 2048 + pos0]; \
    f1_[1] = *(const bf16x8*)&bp_[b_off + (S) * 2048 + pos1]; \
    f1_[2] = *(const bf16x8*)&bp_[b_off + (S) * 2048 + pos2]; \
    f1_[3] = *(const bf16x8*)&bp_[b_off + (S) * 2048 + pos3]; \
    STG; \
    __builtin_amdgcn_s_barrier(); \
    asm volatile("s_waitcnt lgkmcnt(0)" ::: "memory"); \
    __builtin_amdgcn_sched_barrier(0); \
    __builtin_amdgcn_s_setprio(1); \
    _Pragma("unroll") for (int ks_ = 0; ks_ < 4; ++ks_) { \
        acc[S][0] = __builtin_amdgcn_mfma_f32_32x32x16_bf16(f1_[ks_], f2r[0][ks_], acc[S][0], 0, 0, 0); \
        acc[S][1] = __builtin_amdgcn_mfma_f32_32x32x16_bf16(f1_[ks_], f2r[1][ks_], acc[S][1], 0, 0, 0); } \
    __builtin_amdgcn_s_setprio(0); \
    VMC; \
    __builtin_amdgcn_s_barrier(); }

    // prologue: tile0 full (8 segs) + tile1 segs 0-5 -> 14 in flight; drain to 6
    for (int sg = 0; sg < 8; ++sg) STAGE1(0, sg);
    for (int sg = 0; sg < 6; ++sg) STAGE1(1, sg);
    asm volatile("s_waitcnt vmcnt(6)" ::: "memory");
    __builtin_amdgcn_s_barrier();

    int niter = ntiles >> 1;
    for (int i = 0; i < niter; ++i) {
        int t0 = 2 * i, t1 = 2 * i + 1;
        bool more0 = (t0 + 2 < ntiles);
        PHASE(0, 0, true,  { STAGE1(t1, 6); STAGE1(t1, 7); }, {});
        PHASE(0, 1, false, { if (more0) { STAGE1(t0 + 2, 0); STAGE1(t0 + 2, 1); } }, {});
        PHASE(0, 2, false, { if (more0) { STAGE1(t0 + 2, 2); STAGE1(t0 + 2, 3); } }, {});
        PHASE(0, 3, false, { if (more0) { STAGE1(t0 + 2, 4); STAGE1(t0 + 2, 5); } },
              { if (more0) { asm volatile("s_waitcnt vmcnt(6)" ::: "memory"); }
                else       { asm volatile("s_waitcnt vmcnt(0)" ::: "memory"); } });
        PHASE(1, 0, true,  { if (more0) { STAGE1(t0 + 2, 6); STAGE1(t0 + 2, 7); } }, {});
        PHASE(1, 1, false, { if (more0) { STAGE1(t1 + 2, 0); STAGE1(t1 + 2, 1); } }, {});
        PHASE(1, 2, false, { if (more0) { STAGE1(t1 + 2, 2); STAGE1(t1 + 2, 3); } }, {});
        PHASE(1, 3, false, { if (more0) { STAGE1(t1 + 2, 4); STAGE1(t1 + 2, 5); } },
              { if (more0) { asm volatile("s_waitcnt vmcnt(6)" ::: "memory"); } });
    }
#undef PHASE
#undef STAGE1

    __syncthreads();
    float* red = (float*)&ldsbuf[32768];   // overlay buf1 (pipeline done)
    if (main_) {
        float* tbuf = (float*)ldsbuf;      // [256][17] floats, overlay buf0
        if (tid < 32) red[tid] = 0.f;
        __syncthreads();
        // acc[s][t][reg] = C'[n = n0+wB*128+s*32+row32][b = b0+wS*64+t*32+l31]
        // row32 = (reg&3)+8*(reg>>2)+4h; m = row32&15; kcol pair per s.
        float ls[8] = {}, ls2[8] = {};
#pragma unroll
        for (int t = 0; t < 2; ++t) {
            int bloc = wS * 64 + t * 32 + l31;
            float4 t4a = *(const float4*)&Tmat[(b0 + bloc) * 16 + 4 * h];
            float4 t4b = *(const float4*)&Tmat[(b0 + bloc) * 16 + 8 + 4 * h];
            const float* ta = (const float*)&t4a;
            const float* tb = (const float*)&t4b;
#pragma unroll
            for (int s = 0; s < 4; ++s) {
#pragma unroll
                for (int c = 0; c < 2; ++c) {
                    int br = c * 8;
                    float v = acc[s][t][br + 0] * ta[0] + acc[s][t][br + 1] * ta[1]
                            + acc[s][t][br + 2] * ta[2] + acc[s][t][br + 3] * ta[3]
                            + acc[s][t][br + 4] * tb[0] + acc[s][t][br + 5] * tb[1]
                            + acc[s][t][br + 6] * tb[2] + acc[s][t][br + 7] * tb[3];
                    v += __shfl_xor(v, 32);
                    ls[s * 2 + c] += v; ls2[s * 2 + c] += v * v;
                    if (lane < 32) tbuf[bloc * 17 + wB * 8 + s * 2 + c] = v;
                }
            }
        }
#pragma unroll
        for (int idx = 0; idx < 8; ++idx) {
            float a = ls[idx], b2 = ls2[idx];
            a += __shfl_xor(a, 1, 32);  b2 += __shfl_xor(b2, 1, 32);
            a += __shfl_xor(a, 2, 32);  b2 += __shfl_xor(b2, 2, 32);
            a += __shfl_xor(a, 4, 32);  b2 += __shfl_xor(b2, 4, 32);
            a += __shfl_xor(a, 8, 32);  b2 += __shfl_xor(b2, 8, 32);
            a += __shfl_xor(a, 16, 32); b2 += __shfl_xor(b2, 16, 32);
            if (lane == 0) {
                atomicAdd(&red[wB * 8 + idx], a);
                atomicAdd(&red[16 + wB * 8 + idx], b2);
            }
        }
        __syncthreads();
        if (tid < 16) {
            atomicAdd(&ACC[(n0 >> 4) + tid], red[tid]);
            atomicAdd(&ACC[800 + (n0 >> 4) + tid], red[16 + tid]);
        }
        {
            int rowl = tid >> 1, kcb = (tid & 1) * 8;
            float o0 = tbuf[rowl * 17 + kcb + 0];
            float o1 = tbuf[rowl * 17 + kcb + 1];
            float o2 = tbuf[rowl * 17 + kcb + 2];
            float o3 = tbuf[rowl * 17 + kcb + 3];
            float o4 = tbuf[rowl * 17 + kcb + 4];
            float o5 = tbuf[rowl * 17 + kcb + 5];
            float o6 = tbuf[rowl * 17 + kcb + 6];
            float o7 = tbuf[rowl * 17 + kcb + 7];
            float* dst = &TH[(b0 + rowl) * DEEP_ + (n0 >> 4) + kcb];
            *(float4*)dst = make_float4(o0, o1, o2, o3);
            *(float4*)(dst + 4) = make_float4(o4, o5, o6, o7);
        }
    } else {
        red[tid] = 0.f;
        __syncthreads();
        // acc[s][t][reg] = C[b = b0+wB*128+s*32+row32][n = n0+wS*64+t*32+l31]
#pragma unroll
        for (int t = 0; t < 2; ++t) {
            int ncl = wS * 64 + t * 32 + l31;
            int nc = n0 + ncl;
            float ls = 0.f, ls2 = 0.f;
#pragma unroll
            for (int s = 0; s < 4; ++s) {
#pragma unroll
                for (int reg = 0; reg < 16; ++reg) {
                    float v = acc[s][t][reg];
                    int row32 = (reg & 3) + 8 * (reg >> 2) + 4 * h;
                    int brow = b0 + wB * 128 + s * 32 + row32;
                    if (nc < DEEP_) EMB[brow * DEEP_ + nc] = v;
                    ls += v; ls2 += v * v;
                }
            }
            if (nc < DEEP_) {
                atomicAdd(&red[ncl], ls);
                atomicAdd(&red[256 + ncl], ls2);
            }
        }
        __syncthreads();
        if (tid < 256) {
            int nc = n0 + tid;
            if (nc < DEEP_) {
                atomicAdd(&ACC[400 + nc], red[tid]);
                atomicAdd(&ACC[1200 + nc], red[256 + tid]);
            }
        }
    }
}

// ---------------- final BN + ReLU + FC + sigmoid (R11) -------------------------
__global__ __launch_bounds__(256) void kfinal(const float* __restrict__ fig,
                                              const float* __restrict__ fibeta,
                                              const float* __restrict__ eg,
                                              const float* __restrict__ ebeta,
                                              const float* __restrict__ fcw,
                                              const float* __restrict__ fcb,
                                              const float* __restrict__ ws,
                                              float* __restrict__ out) {
    int b = blockIdx.x, tid = threadIdx.x;
    float part = 0.f;
    if (tid < 200) {
        int c = tid * 4;
        int loc = (c < DEEP_) ? c : c - DEEP_;
        const float* xp = (c < DEEP_) ? &ws[OFF_TH + b * DEEP_ + loc]
                                      : &ws[OFF_EMB + b * DEEP_ + loc];
        float4 x = *(const float4*)xp;
        float4 g = *(const float4*)((c < DEEP_) ? &fig[loc] : &eg[loc]);
        float4 be = *(const float4*)((c < DEEP_) ? &fibeta[loc] : &ebeta[loc]);
        float4 sm = *(const float4*)&ws[OFF_ACC + c];
        float4 sq = *(const float4*)&ws[OFF_ACC + 800 + c];
        float4 w = *(const float4*)&fcw[c];
        const float* xv_ = (const float*)&x; const float* gv = (const float*)&g;
        const float* bev = (const float*)&be; const float* smv = (const float*)&sm;
        const float* sqv = (const float*)&sq; const float* wv = (const float*)&w;
#pragma unroll
        for (int j = 0; j < 4; ++j) {
            float mean = smv[j] * (1.f / BATCH);
            float var = sqv[j] * (1.f / BATCH) - mean * mean;
            float rstd = rsqrtf(var + EPS_);
            float v = fmaxf(gv[j] * (xv_[j] - mean) * rstd + bev[j], 0.f);
            part += v * wv[j];
        }
    }
    __shared__ float red[4];
#pragma unroll
    for (int off = 32; off > 0; off >>= 1) part += __shfl_down(part, off, 64);
    if ((tid & 63) == 0) red[tid >> 6] = part;
    __syncthreads();
    if (tid == 0) {
        float tot = red[0] + red[1] + red[2] + red[3] + fcb[0];
        out[b] = 1.f / (1.f + expf(-tot));
    }
}

extern "C" void kernel_launch(void* const* d_in, const int* in_sizes, int n_in,
                              void* d_out, int out_size, void* d_ws, size_t ws_size,
                              hipStream_t stream) {
    const int*   xi    = (const int*)d_in[0];
    const float* xv    = (const float*)d_in[1];
    const float* emb   = (const float*)d_in[2];
    const float* T3    = (const float*)d_in[3];
    const float* T2    = (const float*)d_in[4];
    const float* gc    = (const float*)d_in[5];
    const float* fi_w  = (const float*)d_in[6];
    const float* fig   = (const float*)d_in[8];
    const float* fibt  = (const float*)d_in[9];
    const float* emb_w = (const float*)d_in[10];
    const float* eg    = (const float*)d_in[12];
    const float* ebt   = (const float*)d_in[13];
    const float* fcw   = (const float*)d_in[14];
    const float* fcb   = (const float*)d_in[15];
    float* ws = (float*)d_ws;
    ushort* Abf = (ushort*)(ws + OFF_ABF);
    ushort* W2  = (ushort*)(ws + OFF_W2);
    ushort* WE  = (ushort*)(ws + OFF_WE);
    ushort* FMB = (ushort*)(ws + OFF_FMB);
    float* out = (float*)d_out;

    hipLaunchKernelGGL(kbig, dim3(BATCH + 1536 + 80), dim3(256), 0, stream,
                       xi, xv, emb, gc, fi_w, emb_w, T3, T2, ws, Abf, FMB, W2, WE);
    hipLaunchKernelGGL(kgemms, dim3(432), dim3(512), 0, stream,
                       Abf, W2, FMB, WE, ws + OFF_T, ws + OFF_TH, ws + OFF_EMB, ws + OFF_ACC);
    hipLaunchKernelGGL(kfinal, dim3(BATCH), dim3(256), 0, stream,
                       fig, fibt, eg, ebt, fcw, fcb, ws, out);
}

// Round 18
// 82.812 us; speedup vs baseline: 1.0540x; 1.0540x over previous
//
#include <hip/hip_runtime.h>
#include <hip/hip_bf16.h>

#define BATCH 4096
#define FIELDS_ 39
#define NUMF 13
#define CATF 26
#define DD 16
#define MM 16
#define VV 100000
#define DEEP_ 400
#define QQ 741
#define QPAD 768
#define KE 624      // FIELDS*D
#define KEP 640     // padded K for emb branch
#define NEP 512     // padded N for emb branch
#define N1 6400     // DEEP*M (n = kcol*16 + m)
#define NT_ 24      // QPAD/32 K-tiles (BK=32) for main GEMM  << the round-17 bug: was 12
#define NKTE 20     // KEP/32 K-tiles for emb GEMM
#define EPS_ 1e-5f

// workspace layout (float offsets)
#define OFF_ABF 0                            // ushort A[b][768] row-major
#define OFF_T   (BATCH*QPAD/2)               // f32 softmax[b][m] (t2s folded into W2)
#define OFF_W2  (OFF_T + BATCH*MM)           // ushort W2[n][768] row-major, pre-scaled by t2s[m]
#define OFF_WE  (OFF_W2 + N1*QPAD/2)         // ushort WE[n][640] row-major (n pad 512)
#define OFF_FMB (OFF_WE + NEP*KEP/2)         // ushort fm2[b][k] stride KEP
#define OFF_TH  (OFF_FMB + BATCH*KEP/2)      // f32 th_pre[b][400]
#define OFF_EMB (OFF_TH + BATCH*DEEP_)       // f32 emb_pre[b][400]
#define OFF_ACC (OFF_EMB + BATCH*DEEP_)      // [0:800] sums, [800:1600] sumsq

typedef __attribute__((ext_vector_type(8))) short bf16x8;
typedef __attribute__((ext_vector_type(4))) float f32x4;

__device__ __forceinline__ ushort f2bf(float v) {
    union { float f; unsigned u; } x; x.f = v;
    unsigned r = x.u + 0x7fff + ((x.u >> 16) & 1);
    return (ushort)(r >> 16);
}
__device__ __forceinline__ unsigned pack2(float a, float b) {
    return (unsigned)f2bf(a) | ((unsigned)f2bf(b) << 16);
}
__device__ __forceinline__ void async16(void* lds, const void* g) {
    __builtin_amdgcn_global_load_lds(
        (const __attribute__((address_space(1))) unsigned int*)g,
        (__attribute__((address_space(3))) unsigned int*)lds,
        16, 0, 0);
}

// ---------------- merged: feat | W2 transpose+scale | WE transpose -------------
__global__ __launch_bounds__(256) void kbig(const int* __restrict__ xi,
                                            const float* __restrict__ xv,
                                            const float* __restrict__ emb,
                                            const float* __restrict__ gc,
                                            const float* __restrict__ fi_w,
                                            const float* __restrict__ emb_w,
                                            const float* __restrict__ T3,
                                            const float* __restrict__ T2,
                                            float* __restrict__ ws,
                                            ushort* __restrict__ Abf,
                                            ushort* __restrict__ FMB,
                                            ushort* __restrict__ W2,
                                            ushort* __restrict__ WE) {
    __shared__ float smem[4200];
    int bid = blockIdx.x, tid = threadIdx.x;

    if (bid < BATCH) {
        float* row = smem;
        float* hsh = smem + 624;
        float* gash = smem + 640;
        ushort* stA = (ushort*)(smem + 656);
        ushort* stF = stA + QPAD;
        int b = bid;
        for (int e = tid; e < KE; e += 256) {
            int f = e >> 4, d = e & 15;
            float v;
            if (f < NUMF) {
                v = xv[b * NUMF + f] * emb[(long)f * VV * DD + d];
            } else {
                int c = f - NUMF;
                int idxv = xi[b * CATF + c];
                v = emb[((long)(NUMF + c) * VV + idxv) * DD + d];
            }
            row[e] = v;
        }
        __syncthreads();
        for (int e = tid; e < KEP; e += 256)
            stF[e] = (e < KE) ? f2bf(row[e]) : (ushort)0;
        if (tid < DD) {
            float s = 0.f, s2 = 0.f;
            for (int f = 0; f < FIELDS_; ++f) { float v = row[f * DD + tid]; s += v; s2 += v * v; }
            hsh[tid] = 0.5f * (s * s - s2);
        }
        __syncthreads();
        if (tid < MM) {
            float g = 0.f;
            for (int d = 0; d < DD; ++d) g += hsh[d] * T3[(d * MM + tid) * DD + d];
            gash[tid] = g;
        }
        __syncthreads();
        if (tid < MM) {
            float mx = -1e30f;
            for (int m = 0; m < MM; ++m) mx = fmaxf(mx, gash[m]);
            float se = 0.f;
            for (int m = 0; m < MM; ++m) se += expf(gash[m] - mx);
            ws[OFF_T + b * MM + tid] = expf(gash[tid] - mx) / se;
        }
        for (int q = tid; q < QPAD; q += 256) {
            float av = 0.f;
            if (q < QQ) {
                // closed-form i: largest i with i*(77-i)/2 <= q  (F=39)
                int i = (int)((77.0f - sqrtf(5929.0f - 8.0f * (float)q)) * 0.5f);
                if ((i + 1) * (76 - i) / 2 <= q) ++i;
                if (i * (77 - i) / 2 > q) --i;
                int j = i + 1 + (q - i * (77 - i) / 2);
                const float4* ri = (const float4*)&row[i * DD];
                const float4* rj = (const float4*)&row[j * DD];
                float4 a0 = ri[0], a1 = ri[1], a2 = ri[2], a3 = ri[3];
                float4 b0 = rj[0], b1 = rj[1], b2 = rj[2], b3 = rj[3];
                float dot = a0.x * b0.x + a0.y * b0.y + a0.z * b0.z + a0.w * b0.w
                          + a1.x * b1.x + a1.y * b1.y + a1.z * b1.z + a1.w * b1.w
                          + a2.x * b2.x + a2.y * b2.y + a2.z * b2.z + a2.w * b2.w
                          + a3.x * b3.x + a3.y * b3.y + a3.z * b3.z + a3.w * b3.w;
                av = dot * gc[q];
            }
            stA[q] = f2bf(av);
        }
        __syncthreads();
        if (tid < 96)
            *(uint4*)&Abf[(long)b * QPAD + tid * 8] = *(uint4*)&stA[tid * 8];
        else if (tid < 176)
            *(uint4*)&FMB[(long)b * KEP + (tid - 96) * 8] = *(uint4*)&stF[(tid - 96) * 8];
    } else if (bid < BATCH + 1536) {
        int bt = bid - BATCH;
        int kt = bt >> 6, m = (bt >> 2) & 15, ch = bt & 3;
        float* tile = smem;
        {
            float p = T2[m * DD * DD + tid];
#pragma unroll
            for (int off = 32; off > 0; off >>= 1) p += __shfl_down(p, off, 64);
            if ((tid & 63) == 0) smem[4100 + (tid >> 6)] = p;
        }
        for (int i = tid; i < 32 * 25; i += 256) {
            int ql = i / 25, c4 = i - ql * 25;
            int q = kt * 32 + ql;
            float4 v = make_float4(0.f, 0.f, 0.f, 0.f);
            if (q < QQ) v = *(const float4*)&fi_w[(q * MM + m) * DEEP_ + ch * 100 + c4 * 4];
            tile[ql * 101 + c4 * 4 + 0] = v.x; tile[ql * 101 + c4 * 4 + 1] = v.y;
            tile[ql * 101 + c4 * 4 + 2] = v.z; tile[ql * 101 + c4 * 4 + 3] = v.w;
        }
        __syncthreads();
        float t2s = smem[4100] + smem[4101] + smem[4102] + smem[4103];
        for (int i = tid; i < 100 * 4; i += 256) {
            int lc = i >> 2, cq = i & 3;
            int kcol = ch * 100 + lc;
            unsigned r[4];
#pragma unroll
            for (int j = 0; j < 4; ++j)
                r[j] = pack2(tile[(cq * 8 + 2 * j) * 101 + lc] * t2s,
                             tile[(cq * 8 + 2 * j + 1) * 101 + lc] * t2s);
            *(uint4*)&W2[(long)(kcol * 16 + m) * QPAD + kt * 32 + cq * 8] =
                make_uint4(r[0], r[1], r[2], r[3]);
        }
    } else {
        int bt = bid - BATCH - 1536;
        if (bt == 0) {
            for (int i = tid; i < 1600; i += 256) ws[OFF_ACC + i] = 0.f;
        }
        int kt = bt >> 2, ch = bt & 3;
        float* tile = smem;
        for (int i = tid; i < 32 * 32; i += 256) {
            int kl = i >> 5, c4 = i & 31;
            int k = kt * 32 + kl;
            int n = ch * 128 + c4 * 4;
            float4 v = make_float4(0.f, 0.f, 0.f, 0.f);
            if (k < KE && n < DEEP_) v = *(const float4*)&emb_w[k * DEEP_ + n];
            tile[kl * 129 + c4 * 4 + 0] = v.x; tile[kl * 129 + c4 * 4 + 1] = v.y;
            tile[kl * 129 + c4 * 4 + 2] = v.z; tile[kl * 129 + c4 * 4 + 3] = v.w;
        }
        __syncthreads();
        for (int i = tid; i < 128 * 4; i += 256) {
            int nl = i >> 2, cq = i & 3;
            int n = ch * 128 + nl;
            uint4 o = make_uint4(0, 0, 0, 0);
            if (n < DEEP_) {
                unsigned r[4];
#pragma unroll
                for (int j = 0; j < 4; ++j)
                    r[j] = pack2(tile[(cq * 8 + 2 * j) * 129 + nl], tile[(cq * 8 + 2 * j + 1) * 129 + nl]);
                o = make_uint4(r[0], r[1], r[2], r[3]);
            }
            if (n < NEP)
                *(uint4*)&WE[(long)n * KEP + kt * 32 + cq * 8] = o;
        }
    }
}

// ---------------- unified GEMM dispatch (R11 best: 3-slot vmcnt(4)) ------------
__device__ __forceinline__ void pipeline3(const ushort* p0, const ushort* p1,
                                          const ushort* p2, const ushort* p3,
                                          ushort* lds, int tid, int nt,
                                          int f1b, int f2b, int sw,
                                          f32x4 (*acc)[4]) {
#define STAGEP(SL, T) { \
    ushort* L_ = lds + (SL) * 16384; \
    async16(L_ + tid * 8,         p0 + (T) * 32); \
    async16(L_ + 4096 + tid * 8,  p1 + (T) * 32); \
    async16(L_ + 8192 + tid * 8,  p2 + (T) * 32); \
    async16(L_ + 12288 + tid * 8, p3 + (T) * 32); }
    STAGEP(0, 0); STAGEP(1, 1);
    asm volatile("s_waitcnt vmcnt(4)" ::: "memory");
    __builtin_amdgcn_s_barrier();
    int sl = 0;
    for (int t = 0; t < nt; ++t) {
        __builtin_amdgcn_sched_barrier(0);
        const ushort* cur = lds + sl * 16384;
        bf16x8 f1[8], f2[4];
#pragma unroll
        for (int r = 0; r < 8; ++r) f1[r] = *(const bf16x8*)&cur[f1b + r * 512 + sw];
#pragma unroll
        for (int c = 0; c < 4; ++c) f2[c] = *(const bf16x8*)&cur[f2b + c * 512 + sw];
        int sl2 = sl + 2; if (sl2 >= 3) sl2 -= 3;
        if (t + 2 < nt) STAGEP(sl2, t + 2);
        __builtin_amdgcn_s_setprio(1);
#pragma unroll
        for (int r = 0; r < 8; ++r)
#pragma unroll
            for (int c = 0; c < 4; ++c)
                acc[r][c] = __builtin_amdgcn_mfma_f32_16x16x32_bf16(f1[r], f2[c], acc[r][c], 0, 0, 0);
        __builtin_amdgcn_s_setprio(0);
        if (t + 1 < nt) {
            if (t + 2 < nt) { asm volatile("s_waitcnt vmcnt(4)" ::: "memory"); }
            else            { asm volatile("s_waitcnt vmcnt(0)" ::: "memory"); }
            __builtin_amdgcn_s_barrier();
        }
        sl = sl + 1; if (sl >= 3) sl -= 3;
    }
#undef STAGEP
}

__global__ __launch_bounds__(512, 2) void kgemms(const ushort* __restrict__ Abf,
                                                 const ushort* __restrict__ W2,
                                                 const ushort* __restrict__ FMB,
                                                 const ushort* __restrict__ WE,
                                                 const float* __restrict__ Tmat,
                                                 float* __restrict__ TH,
                                                 float* __restrict__ EMB,
                                                 float* __restrict__ ACC) {
    __shared__ ushort ldsbuf[3 * 16384];   // slot: A[256][32] | B[256][32]
    __shared__ float red[512];
    int tid = threadIdx.x;
    int lane = tid & 63, wid = tid >> 6;
    int wB = wid >> 2;        // 0..1: 128-row side (f1)
    int wS = wid & 3;         // 0..3: 64-row side (f2)
    int kq = lane >> 4, lr = lane & 15;
    int rr = tid >> 2, ac = tid & 3;
    int csw = (ac ^ ((rr >> 1) & 3)) * 8;   // inverse-swizzled global source
    int sw = (kq ^ ((lr >> 1) & 3)) * 8;    // swizzled LDS fragment read
    red[tid] = 0.f;
    f32x4 acc[8][4] = {};
    int wg = blockIdx.x;

    if (wg < 400) {
        // main GEMM, operand-swapped: f1 = W (n, 128-side), f2 = A (b, 64-side)
        int s = (wg & 7) * 50 + (wg >> 3);     // XCD swizzle (400 % 8 == 0)
        int b0 = (s / 25) * 256;
        int n0 = (s % 25) * 256;
        const ushort* p0 = Abf + (long)(b0 + rr) * QPAD + csw;
        const ushort* p1 = Abf + (long)(b0 + 128 + rr) * QPAD + csw;
        const ushort* p2 = W2 + (long)(n0 + rr) * QPAD + csw;
        const ushort* p3 = W2 + (long)(n0 + 128 + rr) * QPAD + csw;
        pipeline3(p0, p1, p2, p3, ldsbuf, tid, NT_,
                  8192 + (wB * 128 + lr) * 32, (wS * 64 + lr) * 32, sw, acc);
        // acc[r][cg][j] = C'[n = n0+wB*128+r*16+kq*4+j][b = b0+wS*64+cg*16+lr]
        float* tbuf = (float*)ldsbuf;          // [256][17] floats, inside slot 0
        float ls[8] = {}, ls2[8] = {};
#pragma unroll
        for (int cg = 0; cg < 4; ++cg) {
            int bloc = wS * 64 + cg * 16 + lr;
            float4 t4 = *(const float4*)&Tmat[(b0 + bloc) * 16 + kq * 4];
#pragma unroll
            for (int r = 0; r < 8; ++r) {
                float v = acc[r][cg][0] * t4.x + acc[r][cg][1] * t4.y +
                          acc[r][cg][2] * t4.z + acc[r][cg][3] * t4.w;
                v += __shfl_xor(v, 16);
                v += __shfl_xor(v, 32);
                ls[r] += v; ls2[r] += v * v;
                if (lane < 16) tbuf[bloc * 17 + wB * 8 + r] = v;
            }
        }
#pragma unroll
        for (int r = 0; r < 8; ++r) {
            float a = ls[r], b2 = ls2[r];
            a += __shfl_xor(a, 8, 16); b2 += __shfl_xor(b2, 8, 16);
            a += __shfl_xor(a, 4, 16); b2 += __shfl_xor(b2, 4, 16);
            a += __shfl_xor(a, 2, 16); b2 += __shfl_xor(b2, 2, 16);
            a += __shfl_xor(a, 1, 16); b2 += __shfl_xor(b2, 1, 16);
            if (lane == 0) {
                atomicAdd(&red[wB * 8 + r], a);
                atomicAdd(&red[16 + wB * 8 + r], b2);
            }
        }
        __syncthreads();
        if (tid < 16) {
            atomicAdd(&ACC[(n0 >> 4) + tid], red[tid]);
            atomicAdd(&ACC[800 + (n0 >> 4) + tid], red[16 + tid]);
        }
        {
            int rowl = tid >> 1, kcb = (tid & 1) * 8;
            float o0 = tbuf[rowl * 17 + kcb + 0];
            float o1 = tbuf[rowl * 17 + kcb + 1];
            float o2 = tbuf[rowl * 17 + kcb + 2];
            float o3 = tbuf[rowl * 17 + kcb + 3];
            float o4 = tbuf[rowl * 17 + kcb + 4];
            float o5 = tbuf[rowl * 17 + kcb + 5];
            float o6 = tbuf[rowl * 17 + kcb + 6];
            float o7 = tbuf[rowl * 17 + kcb + 7];
            float* dst = &TH[(b0 + rowl) * DEEP_ + (n0 >> 4) + kcb];
            *(float4*)dst = make_float4(o0, o1, o2, o3);
            *(float4*)(dst + 4) = make_float4(o4, o5, o6, o7);
        }
    } else {
        int e = wg - 400;
        int se = (e & 7) * 4 + (e >> 3);       // 32 % 8 == 0
        int b0 = (se >> 1) * 256;
        int n0 = (se & 1) * 256;
        const ushort* p0 = FMB + (long)(b0 + rr) * KEP + csw;
        const ushort* p1 = FMB + (long)(b0 + 128 + rr) * KEP + csw;
        const ushort* p2 = WE + (long)(n0 + rr) * KEP + csw;
        const ushort* p3 = WE + (long)(n0 + 128 + rr) * KEP + csw;
        pipeline3(p0, p1, p2, p3, ldsbuf, tid, NKTE,
                  (wB * 128 + lr) * 32, 8192 + (wS * 64 + lr) * 32, sw, acc);
        // acc[r][cg][j] = C[b = b0+wB*128+r*16+kq*4+j][n = n0+wS*64+cg*16+lr]
#pragma unroll
        for (int cg = 0; cg < 4; ++cg) {
            int ncl = wS * 64 + cg * 16 + lr;
            int nc = n0 + ncl;
            float ls = 0.f, ls2 = 0.f;
#pragma unroll
            for (int r = 0; r < 8; ++r) {
#pragma unroll
                for (int j = 0; j < 4; ++j) {
                    float v = acc[r][cg][j];
                    int brow = b0 + wB * 128 + r * 16 + kq * 4 + j;
                    if (nc < DEEP_) EMB[brow * DEEP_ + nc] = v;
                    ls += v; ls2 += v * v;
                }
            }
            ls += __shfl_xor(ls, 16);  ls += __shfl_xor(ls, 32);
            ls2 += __shfl_xor(ls2, 16); ls2 += __shfl_xor(ls2, 32);
            if (lane < 16 && nc < DEEP_) {
                atomicAdd(&red[ncl], ls);
                atomicAdd(&red[256 + ncl], ls2);
            }
        }
        __syncthreads();
        if (tid < 256) {
            int nc = n0 + tid;
            if (nc < DEEP_) {
                atomicAdd(&ACC[400 + nc], red[tid]);
                atomicAdd(&ACC[1200 + nc], red[256 + tid]);
            }
        }
    }
}

// ---------------- final BN + ReLU + FC + sigmoid (R11) -------------------------
__global__ __launch_bounds__(256) void kfinal(const float* __restrict__ fig,
                                              const float* __restrict__ fibeta,
                                              const float* __restrict__ eg,
                                              const float* __restrict__ ebeta,
                                              const float* __restrict__ fcw,
                                              const float* __restrict__ fcb,
                                              const float* __restrict__ ws,
                                              float* __restrict__ out) {
    int b = blockIdx.x, tid = threadIdx.x;
    float part = 0.f;
    if (tid < 200) {
        int c = tid * 4;
        int loc = (c < DEEP_) ? c : c - DEEP_;
        const float* xp = (c < DEEP_) ? &ws[OFF_TH + b * DEEP_ + loc]
                                      : &ws[OFF_EMB + b * DEEP_ + loc];
        float4 x = *(const float4*)xp;
        float4 g = *(const float4*)((c < DEEP_) ? &fig[loc] : &eg[loc]);
        float4 be = *(const float4*)((c < DEEP_) ? &fibeta[loc] : &ebeta[loc]);
        float4 sm = *(const float4*)&ws[OFF_ACC + c];
        float4 sq = *(const float4*)&ws[OFF_ACC + 800 + c];
        float4 w = *(const float4*)&fcw[c];
        const float* xv_ = (const float*)&x; const float* gv = (const float*)&g;
        const float* bev = (const float*)&be; const float* smv = (const float*)&sm;
        const float* sqv = (const float*)&sq; const float* wv = (const float*)&w;
#pragma unroll
        for (int j = 0; j < 4; ++j) {
            float mean = smv[j] * (1.f / BATCH);
            float var = sqv[j] * (1.f / BATCH) - mean * mean;
            float rstd = rsqrtf(var + EPS_);
            float v = fmaxf(gv[j] * (xv_[j] - mean) * rstd + bev[j], 0.f);
            part += v * wv[j];
        }
    }
    __shared__ float red[4];
#pragma unroll
    for (int off = 32; off > 0; off >>= 1) part += __shfl_down(part, off, 64);
    if ((tid & 63) == 0) red[tid >> 6] = part;
    __syncthreads();
    if (tid == 0) {
        float tot = red[0] + red[1] + red[2] + red[3] + fcb[0];
        out[b] = 1.f / (1.f + expf(-tot));
    }
}

extern "C" void kernel_launch(void* const* d_in, const int* in_sizes, int n_in,
                              void* d_out, int out_size, void* d_ws, size_t ws_size,
                              hipStream_t stream) {
    const int*   xi    = (const int*)d_in[0];
    const float* xv    = (const float*)d_in[1];
    const float* emb   = (const float*)d_in[2];
    const float* T3    = (const float*)d_in[3];
    const float* T2    = (const float*)d_in[4];
    const float* gc    = (const float*)d_in[5];
    const float* fi_w  = (const float*)d_in[6];
    const float* fig   = (const float*)d_in[8];
    const float* fibt  = (const float*)d_in[9];
    const float* emb_w = (const float*)d_in[10];
    const float* eg    = (const float*)d_in[12];
    const float* ebt   = (const float*)d_in[13];
    const float* fcw   = (const float*)d_in[14];
    const float* fcb   = (const float*)d_in[15];
    float* ws = (float*)d_ws;
    ushort* Abf = (ushort*)(ws + OFF_ABF);
    ushort* W2  = (ushort*)(ws + OFF_W2);
    ushort* WE  = (ushort*)(ws + OFF_WE);
    ushort* FMB = (ushort*)(ws + OFF_FMB);
    float* out = (float*)d_out;

    hipLaunchKernelGGL(kbig, dim3(BATCH + 1536 + 80), dim3(256), 0, stream,
                       xi, xv, emb, gc, fi_w, emb_w, T3, T2, ws, Abf, FMB, W2, WE);
    hipLaunchKernelGGL(kgemms, dim3(432), dim3(512), 0, stream,
                       Abf, W2, FMB, WE, ws + OFF_T, ws + OFF_TH, ws + OFF_EMB, ws + OFF_ACC);
    hipLaunchKernelGGL(kfinal, dim3(BATCH), dim3(256), 0, stream,
                       fig, fibt, eg, ebt, fcw, fcb, ws, out);
}